// Round 1
// baseline (840.571 us; speedup 1.0000x reference)
//
#include <hip/hip_runtime.h>

#define B_ 4
#define H_ 16
#define N_ 1024
#define C_ 64
#define D_ 1024

// ---------------------------------------------------------------------------
// Kernel 1: xpe[b, n, h*C + c] = sum_m pe[h, n, m] * v[b, h, m, c]
// (the post-softmax pe bias contribution, pulled out as a clean GEMM)
// ---------------------------------------------------------------------------
__global__ __launch_bounds__(256) void pev_kernel(
    const float* __restrict__ pe, const float* __restrict__ v,
    float* __restrict__ xpe)
{
  __shared__ __align__(16) float At[64][68];  // [k][n-row] (transposed pe tile)
  __shared__ __align__(16) float Bs[64][68];  // [k][c]     (v tile)
  const int tid = threadIdx.x;
  const int n0 = blockIdx.x * 64;
  const int bh = blockIdx.y;
  const int h = bh & (H_ - 1);
  const int b = bh >> 4;
  const float* __restrict__ peb = pe + (size_t)h * N_ * N_;
  const float* __restrict__ vb  = v  + (size_t)(b * H_ + h) * N_ * C_;
  const int ty = tid >> 4, tx = tid & 15;
  float acc[4][4] = {};

  for (int k0 = 0; k0 < N_; k0 += 64) {
    __syncthreads();
#pragma unroll
    for (int i0 = 0; i0 < 4; ++i0) {
      int i = i0 * 256 + tid;
      int r = i >> 4, c4 = (i & 15) << 2;
      float4 a = *(const float4*)(peb + (size_t)(n0 + r) * N_ + (k0 + c4));
      At[c4 + 0][r] = a.x; At[c4 + 1][r] = a.y;
      At[c4 + 2][r] = a.z; At[c4 + 3][r] = a.w;
      *(float4*)&Bs[r][c4] = *(const float4*)(vb + (size_t)(k0 + r) * C_ + c4);
    }
    __syncthreads();
#pragma unroll 8
    for (int kk = 0; kk < 64; ++kk) {
      float4 av = *(const float4*)&At[kk][ty << 2];
      float4 bv = *(const float4*)&Bs[kk][tx << 2];
      float aa[4] = {av.x, av.y, av.z, av.w};
      float bb[4] = {bv.x, bv.y, bv.z, bv.w};
#pragma unroll
      for (int i = 0; i < 4; ++i)
#pragma unroll
        for (int j = 0; j < 4; ++j)
          acc[i][j] = fmaf(aa[i], bb[j], acc[i][j]);
    }
  }
#pragma unroll
  for (int i = 0; i < 4; ++i) {
    float4 o = make_float4(acc[i][0], acc[i][1], acc[i][2], acc[i][3]);
    *(float4*)(xpe + (size_t)(b * N_ + n0 + (ty << 2) + i) * D_ + h * C_ + (tx << 2)) = o;
  }
}

// ---------------------------------------------------------------------------
// Kernel 2: flash-style softmax attention (pe handled by pev_kernel).
// out[b, n, h*C + c] = (sum_m softmax(qk^T)[n,m] v[m,c]) + xpe[b, n, h*C + c]
// One block per (b, h, 64-row query tile); online softmax over 16 key tiles.
// ---------------------------------------------------------------------------
__global__ __launch_bounds__(256) void attn_kernel(
    const float* __restrict__ q, const float* __restrict__ k,
    const float* __restrict__ v, const float* __restrict__ xpe,
    float* __restrict__ out)
{
  __shared__ __align__(16) float qs[64][68];
  __shared__ __align__(16) float ks[64][68];
  __shared__ __align__(16) float vs[64][68];
  __shared__ __align__(16) float ss[64][68];
  __shared__ float rowm[64], rowl[64], rowa[64];

  const int tid = threadIdx.x;
  const int qt = blockIdx.x & 15;
  const int bh = blockIdx.x >> 4;
  const int h = bh & (H_ - 1);
  const int b = bh >> 4;
  const int q0 = qt * 64;

  const float* __restrict__ qb = q + ((size_t)(b * H_ + h) * N_ + q0) * C_;
  const float* __restrict__ kb = k + (size_t)(b * H_ + h) * N_ * C_;
  const float* __restrict__ vb = v + (size_t)(b * H_ + h) * N_ * C_;

  // stage q tile, pre-scaled by C^-0.5 = 0.125
#pragma unroll
  for (int i0 = 0; i0 < 4; ++i0) {
    int i = i0 * 256 + tid;
    int r = i >> 4, c4 = (i & 15) << 2;
    float4 t = *(const float4*)(qb + (size_t)r * C_ + c4);
    qs[r][c4 + 0] = t.x * 0.125f;
    qs[r][c4 + 1] = t.y * 0.125f;
    qs[r][c4 + 2] = t.z * 0.125f;
    qs[r][c4 + 3] = t.w * 0.125f;
  }
  if (tid < 64) { rowm[tid] = -3.0e38f; rowl[tid] = 0.0f; }

  const int ty = tid >> 4, tx = tid & 15;
  const int r0 = ty << 2;        // 4 query rows per thread
  const int c0 = tx << 2;        // 4 ctx columns per thread (PV phase)
  float accs[4][4] = {};

  for (int kt = 0; kt < 16; ++kt) {
    const int m0 = kt * 64;
    __syncthreads();             // previous PV done; safe to overwrite tiles
#pragma unroll
    for (int i0 = 0; i0 < 4; ++i0) {
      int i = i0 * 256 + tid;
      int r = i >> 4, c4 = (i & 15) << 2;
      *(float4*)&ks[r][c4] = *(const float4*)(kb + (size_t)(m0 + r) * C_ + c4);
      *(float4*)&vs[r][c4] = *(const float4*)(vb + (size_t)(m0 + r) * C_ + c4);
    }
    __syncthreads();

    // scores: s[i][j] = dot(q[r0+i], k[tx + 16j])  (strided cols: bank-friendly)
    float s[4][4] = {};
#pragma unroll 4
    for (int c = 0; c < 64; c += 4) {
      float4 a[4], kv[4];
#pragma unroll
      for (int i = 0; i < 4; ++i) a[i] = *(const float4*)&qs[r0 + i][c];
#pragma unroll
      for (int j = 0; j < 4; ++j) kv[j] = *(const float4*)&ks[tx + (j << 4)][c];
#pragma unroll
      for (int i = 0; i < 4; ++i)
#pragma unroll
        for (int j = 0; j < 4; ++j)
          s[i][j] += a[i].x * kv[j].x + a[i].y * kv[j].y
                   + a[i].z * kv[j].z + a[i].w * kv[j].w;
    }
#pragma unroll
    for (int i = 0; i < 4; ++i)
#pragma unroll
      for (int j = 0; j < 4; ++j)
        ss[r0 + i][tx + (j << 4)] = s[i][j];
    __syncthreads();

    // online softmax update: 4 threads per row (same wave -> lockstep safe)
    {
      const int row = tid >> 2, sub = tid & 3;
      float* srow = &ss[row][sub << 4];
      float4 x0 = *(const float4*)(srow + 0);
      float4 x1 = *(const float4*)(srow + 4);
      float4 x2 = *(const float4*)(srow + 8);
      float4 x3 = *(const float4*)(srow + 12);
      float lm = fmaxf(fmaxf(fmaxf(x0.x, x0.y), fmaxf(x0.z, x0.w)),
                       fmaxf(fmaxf(x1.x, x1.y), fmaxf(x1.z, x1.w)));
      lm = fmaxf(lm, fmaxf(fmaxf(fmaxf(x2.x, x2.y), fmaxf(x2.z, x2.w)),
                           fmaxf(fmaxf(x3.x, x3.y), fmaxf(x3.z, x3.w))));
      lm = fmaxf(lm, __shfl_xor(lm, 1));
      lm = fmaxf(lm, __shfl_xor(lm, 2));
      const float om = rowm[row];
      const float nm = fmaxf(om, lm);
      const float al = __expf(om - nm);
      x0.x = __expf(x0.x - nm); x0.y = __expf(x0.y - nm);
      x0.z = __expf(x0.z - nm); x0.w = __expf(x0.w - nm);
      x1.x = __expf(x1.x - nm); x1.y = __expf(x1.y - nm);
      x1.z = __expf(x1.z - nm); x1.w = __expf(x1.w - nm);
      x2.x = __expf(x2.x - nm); x2.y = __expf(x2.y - nm);
      x2.z = __expf(x2.z - nm); x2.w = __expf(x2.w - nm);
      x3.x = __expf(x3.x - nm); x3.y = __expf(x3.y - nm);
      x3.z = __expf(x3.z - nm); x3.w = __expf(x3.w - nm);
      float sm = x0.x + x0.y + x0.z + x0.w + x1.x + x1.y + x1.z + x1.w
               + x2.x + x2.y + x2.z + x2.w + x3.x + x3.y + x3.z + x3.w;
      *(float4*)(srow + 0)  = x0;
      *(float4*)(srow + 4)  = x1;
      *(float4*)(srow + 8)  = x2;
      *(float4*)(srow + 12) = x3;
      sm += __shfl_xor(sm, 1);
      sm += __shfl_xor(sm, 2);
      if (sub == 0) {
        rowl[row] = rowl[row] * al + sm;
        rowm[row] = nm;
        rowa[row] = al;
      }
    }
    __syncthreads();

    // rescale accumulators, then PV accumulate for this tile
    float alv[4];
#pragma unroll
    for (int i = 0; i < 4; ++i) alv[i] = rowa[r0 + i];
#pragma unroll
    for (int i = 0; i < 4; ++i)
#pragma unroll
      for (int j = 0; j < 4; ++j)
        accs[i][j] *= alv[i];

#pragma unroll 4
    for (int m = 0; m < 64; m += 4) {
      float4 p[4], vv[4];
#pragma unroll
      for (int i = 0; i < 4; ++i) p[i] = *(const float4*)&ss[r0 + i][m];
#pragma unroll
      for (int t = 0; t < 4; ++t) vv[t] = *(const float4*)&vs[m + t][c0];
#pragma unroll
      for (int i = 0; i < 4; ++i) {
        accs[i][0] += p[i].x * vv[0].x + p[i].y * vv[1].x + p[i].z * vv[2].x + p[i].w * vv[3].x;
        accs[i][1] += p[i].x * vv[0].y + p[i].y * vv[1].y + p[i].z * vv[2].y + p[i].w * vv[3].y;
        accs[i][2] += p[i].x * vv[0].z + p[i].y * vv[1].z + p[i].z * vv[2].z + p[i].w * vv[3].z;
        accs[i][3] += p[i].x * vv[0].w + p[i].y * vv[1].w + p[i].z * vv[2].w + p[i].w * vv[3].w;
      }
    }
  }

  float linv[4];
#pragma unroll
  for (int i = 0; i < 4; ++i) linv[i] = 1.0f / rowl[r0 + i];

#pragma unroll
  for (int i = 0; i < 4; ++i) {
    size_t o = (size_t)(b * N_ + q0 + r0 + i) * D_ + h * C_ + c0;
    float4 xp = *(const float4*)(xpe + o);
    float4 ov;
    ov.x = accs[i][0] * linv[i] + xp.x;
    ov.y = accs[i][1] * linv[i] + xp.y;
    ov.z = accs[i][2] * linv[i] + xp.z;
    ov.w = accs[i][3] * linv[i] + xp.w;
    *(float4*)(out + o) = ov;
  }
}

// ---------------------------------------------------------------------------
// Kernel 3/4: Y = X @ W + bias, optional SiLU.  X:[4096,1024] W:[1024,1024]
// ---------------------------------------------------------------------------
template <bool SILU>
__global__ __launch_bounds__(256) void mlp_kernel(
    const float* __restrict__ X, const float* __restrict__ W,
    const float* __restrict__ bias, float* __restrict__ Y)
{
  __shared__ __align__(16) float At[64][68];  // [k][m] transposed X tile
  __shared__ __align__(16) float Bs[64][68];  // [k][n] W tile
  const int tid = threadIdx.x;
  const int n0 = blockIdx.x * 64;
  const int m0 = blockIdx.y * 64;
  const int ty = tid >> 4, tx = tid & 15;
  float acc[4][4] = {};

  for (int k0 = 0; k0 < D_; k0 += 64) {
    __syncthreads();
#pragma unroll
    for (int i0 = 0; i0 < 4; ++i0) {
      int i = i0 * 256 + tid;
      int r = i >> 4, c4 = (i & 15) << 2;
      float4 a = *(const float4*)(X + (size_t)(m0 + r) * D_ + (k0 + c4));
      At[c4 + 0][r] = a.x; At[c4 + 1][r] = a.y;
      At[c4 + 2][r] = a.z; At[c4 + 3][r] = a.w;
      *(float4*)&Bs[r][c4] = *(const float4*)(W + (size_t)(k0 + r) * D_ + (n0 + c4));
    }
    __syncthreads();
#pragma unroll 8
    for (int kk = 0; kk < 64; ++kk) {
      float4 av = *(const float4*)&At[kk][ty << 2];
      float4 bv = *(const float4*)&Bs[kk][tx << 2];
      float aa[4] = {av.x, av.y, av.z, av.w};
      float bb[4] = {bv.x, bv.y, bv.z, bv.w};
#pragma unroll
      for (int i = 0; i < 4; ++i)
#pragma unroll
        for (int j = 0; j < 4; ++j)
          acc[i][j] = fmaf(aa[i], bb[j], acc[i][j]);
    }
  }

  const int n = n0 + (tx << 2);
  float4 bv = *(const float4*)(bias + n);
#pragma unroll
  for (int i = 0; i < 4; ++i) {
    float o0 = acc[i][0] + bv.x;
    float o1 = acc[i][1] + bv.y;
    float o2 = acc[i][2] + bv.z;
    float o3 = acc[i][3] + bv.w;
    if (SILU) {
      o0 *= 1.0f / (1.0f + __expf(-o0));
      o1 *= 1.0f / (1.0f + __expf(-o1));
      o2 *= 1.0f / (1.0f + __expf(-o2));
      o3 *= 1.0f / (1.0f + __expf(-o3));
    }
    *(float4*)(Y + (size_t)(m0 + (ty << 2) + i) * D_ + n) = make_float4(o0, o1, o2, o3);
  }
}

// ---------------------------------------------------------------------------
extern "C" void kernel_launch(void* const* d_in, const int* in_sizes, int n_in,
                              void* d_out, int out_size, void* d_ws, size_t ws_size,
                              hipStream_t stream) {
  const float* q  = (const float*)d_in[0];
  const float* k  = (const float*)d_in[1];
  const float* v  = (const float*)d_in[2];
  const float* pe = (const float*)d_in[3];
  const float* w1 = (const float*)d_in[4];
  const float* b1 = (const float*)d_in[5];
  const float* w2 = (const float*)d_in[6];
  const float* b2 = (const float*)d_in[7];
  float* out = (float*)d_out;
  float* scratch = (float*)d_ws;  // 4096*1024 floats: xpe, later reused as h1

  // 1) xpe = pe @ v  -> scratch
  pev_kernel<<<dim3(N_ / 64, B_ * H_), 256, 0, stream>>>(pe, v, scratch);
  // 2) X = softmax-attention + xpe -> d_out (as [B*N, D])
  attn_kernel<<<dim3(B_ * H_ * (N_ / 64)), 256, 0, stream>>>(q, k, v, scratch, out);
  // 3) h1 = silu(X @ w1 + b1) -> scratch (xpe already consumed)
  mlp_kernel<true><<<dim3(D_ / 64, (B_ * N_) / 64), 256, 0, stream>>>(out, w1, b1, scratch);
  // 4) out = h1 @ w2 + b2 -> d_out
  mlp_kernel<false><<<dim3(D_ / 64, (B_ * N_) / 64), 256, 0, stream>>>(scratch, w2, b2, out);
}

// Round 2
// 427.561 us; speedup vs baseline: 1.9660x; 1.9660x over previous
//
#include <hip/hip_runtime.h>

#define B_ 4
#define H_ 16
#define N_ 1024
#define C_ 64
#define D_ 1024

typedef _Float16 half8 __attribute__((ext_vector_type(8)));
typedef _Float16 half4v __attribute__((ext_vector_type(4)));
typedef float f32x4 __attribute__((ext_vector_type(4)));

#define MFMA16(a, b, c) __builtin_amdgcn_mfma_f32_16x16x32_f16(a, b, c, 0, 0, 0)

// ---------------------------------------------------------------------------
// transpose_cvt: out_f16[c][r] = (f16) in_f32[r][c], 64x64 tiles, batched (z)
// ---------------------------------------------------------------------------
__global__ __launch_bounds__(256) void transpose_cvt(
    const float* __restrict__ in, _Float16* __restrict__ outp,
    int in_stride, int out_stride, long in_bstride, long out_bstride)
{
  __shared__ float t[64][65];
  const int tid = threadIdx.x;
  const int r0 = blockIdx.x * 64, c0 = blockIdx.y * 64;
  const float* inb = in + (size_t)blockIdx.z * in_bstride;
  _Float16* outb = outp + (size_t)blockIdx.z * out_bstride;
#pragma unroll
  for (int i = 0; i < 4; ++i) {
    int idx = i * 256 + tid;
    int r = idx >> 4, c4 = (idx & 15) << 2;
    float4 a = *(const float4*)(inb + (size_t)(r0 + r) * in_stride + c0 + c4);
    t[r][c4] = a.x; t[r][c4 + 1] = a.y; t[r][c4 + 2] = a.z; t[r][c4 + 3] = a.w;
  }
  __syncthreads();
#pragma unroll
  for (int i = 0; i < 2; ++i) {
    int idx = i * 256 + tid;
    int rr = idx >> 3, c8 = (idx & 7) << 3;
    half8 hv;
#pragma unroll
    for (int j = 0; j < 8; ++j) hv[j] = (_Float16)t[c8 + j][rr];
    *(half8*)(outb + (size_t)(c0 + rr) * out_stride + r0 + c8) = hv;
  }
}

// ---------------------------------------------------------------------------
// attn: flash attention with fused pe@V.
// out_f16[b, n, h*64+c] = (softmax(q k^T / 8) @ v)[n,c] + (pe @ v)[n,c]
// Block: 256 thr (4 waves); 64-query tile; wave w owns query rows 16w..16w+15.
// ---------------------------------------------------------------------------
__global__ __launch_bounds__(256) void attn_kernel(
    const float* __restrict__ q, const float* __restrict__ k,
    const float* __restrict__ pe, const _Float16* __restrict__ vth,
    _Float16* __restrict__ Xh)
{
  __shared__ __align__(16) _Float16 qs[64][72];   // [query][c]
  __shared__ __align__(16) _Float16 ks[64][72];   // [key][c]
  __shared__ __align__(16) _Float16 vst[64][72];  // [c][key]   (from vth)
  __shared__ __align__(16) _Float16 pes[64][72];  // [query][key]
  __shared__ __align__(16) _Float16 ps[64][72];   // [query][key] exp(S-m)

  const int tid = threadIdx.x;
  const int qt = blockIdx.x & 15;
  const int bh = blockIdx.x >> 4;
  const int h = bh & (H_ - 1);
  const int b = bh >> 4;
  const int q0 = qt * 64;

  const float* qb = q + ((size_t)bh * N_ + q0) * C_;
  const float* kb = k + (size_t)bh * N_ * C_;
  const float* peb = pe + (size_t)h * N_ * N_ + (size_t)q0 * N_;
  const _Float16* vb = vth + (size_t)bh * C_ * N_;

  // stage q tile once, pre-scaled by C^-0.5 = 0.125
#pragma unroll
  for (int i = 0; i < 4; ++i) {
    int idx = i * 256 + tid;
    int r = idx >> 4, c4 = (idx & 15) << 2;
    float4 t = *(const float4*)(qb + (size_t)r * C_ + c4);
    half4v hv = { (_Float16)(t.x * 0.125f), (_Float16)(t.y * 0.125f),
                  (_Float16)(t.z * 0.125f), (_Float16)(t.w * 0.125f) };
    *(half4v*)&qs[r][c4] = hv;
  }

  const int lane = tid & 63;
  const int w = tid >> 6;
  const int l15 = lane & 15;
  const int quad = lane >> 4;
  const int arow = 16 * w + l15;   // A-fragment row (query) within 64-tile

  f32x4 Os[4], Op[4];
  float m_run[4], l_run[4];
#pragma unroll
  for (int t = 0; t < 4; ++t) {
    Os[t] = (f32x4){0.f, 0.f, 0.f, 0.f};
    Op[t] = (f32x4){0.f, 0.f, 0.f, 0.f};
  }
#pragma unroll
  for (int r = 0; r < 4; ++r) { m_run[r] = -3.0e38f; l_run[r] = 0.f; }

  for (int kt = 0; kt < 16; ++kt) {
    const int m0 = kt * 64;
    __syncthreads();   // everyone done with previous tile's LDS
    // stage K and pe tiles (fp32 -> f16)
#pragma unroll
    for (int i = 0; i < 4; ++i) {
      int idx = i * 256 + tid;
      int r = idx >> 4, c4 = (idx & 15) << 2;
      float4 tk = *(const float4*)(kb + (size_t)(m0 + r) * C_ + c4);
      half4v hk = {(_Float16)tk.x, (_Float16)tk.y, (_Float16)tk.z, (_Float16)tk.w};
      *(half4v*)&ks[r][c4] = hk;
      float4 tp = *(const float4*)(peb + (size_t)r * N_ + m0 + c4);
      half4v hp = {(_Float16)tp.x, (_Float16)tp.y, (_Float16)tp.z, (_Float16)tp.w};
      *(half4v*)&pes[r][c4] = hp;
    }
    // stage V^T tile (already f16, plain copy)
#pragma unroll
    for (int i = 0; i < 2; ++i) {
      int idx = i * 256 + tid;
      int rr = idx >> 3, c8 = (idx & 7) << 3;
      *(uint4*)&vst[rr][c8] = *(const uint4*)(vb + (size_t)rr * N_ + m0 + c8);
    }
    __syncthreads();

    // ---- S = Q K^T (pre-scaled) ----
    f32x4 sacc[4];
#pragma unroll
    for (int t = 0; t < 4; ++t) sacc[t] = (f32x4){0.f, 0.f, 0.f, 0.f};
#pragma unroll
    for (int s = 0; s < 2; ++s) {
      half8 aq = *(const half8*)&qs[arow][s * 32 + quad * 8];
#pragma unroll
      for (int t = 0; t < 4; ++t) {
        half8 bk = *(const half8*)&ks[16 * t + l15][s * 32 + quad * 8];
        sacc[t] = MFMA16(aq, bk, sacc[t]);
      }
    }

    // ---- online softmax (rows quad*4+r, cols across quad's 16 lanes) ----
    float alpha[4];
#pragma unroll
    for (int r = 0; r < 4; ++r) {
      float mx = fmaxf(fmaxf(sacc[0][r], sacc[1][r]), fmaxf(sacc[2][r], sacc[3][r]));
      mx = fmaxf(mx, __shfl_xor(mx, 1));
      mx = fmaxf(mx, __shfl_xor(mx, 2));
      mx = fmaxf(mx, __shfl_xor(mx, 4));
      mx = fmaxf(mx, __shfl_xor(mx, 8));
      float nm = fmaxf(m_run[r], mx);
      alpha[r] = __expf(m_run[r] - nm);
      m_run[r] = nm;
      float rs = 0.f;
#pragma unroll
      for (int t = 0; t < 4; ++t) {
        float p = __expf(sacc[t][r] - nm);
        sacc[t][r] = p;
        rs += p;
      }
      rs += __shfl_xor(rs, 1);
      rs += __shfl_xor(rs, 2);
      rs += __shfl_xor(rs, 4);
      rs += __shfl_xor(rs, 8);
      l_run[r] = l_run[r] * alpha[r] + rs;
    }

    // write P (own strip only -> same-wave LDS, no barrier needed), rescale O
#pragma unroll
    for (int t = 0; t < 4; ++t)
#pragma unroll
      for (int r = 0; r < 4; ++r)
        ps[16 * w + quad * 4 + r][16 * t + l15] = (_Float16)sacc[t][r];
#pragma unroll
    for (int t = 0; t < 4; ++t)
#pragma unroll
      for (int r = 0; r < 4; ++r)
        Os[t][r] *= alpha[r];

    // ---- O_soft += P V ; O_pe += PE V (share V B-fragments) ----
#pragma unroll
    for (int s = 0; s < 2; ++s) {
      half8 ap = *(const half8*)&ps[arow][s * 32 + quad * 8];
      half8 ae = *(const half8*)&pes[arow][s * 32 + quad * 8];
#pragma unroll
      for (int t = 0; t < 4; ++t) {
        half8 bv = *(const half8*)&vst[16 * t + l15][s * 32 + quad * 8];
        Os[t] = MFMA16(ap, bv, Os[t]);
        Op[t] = MFMA16(ae, bv, Op[t]);
      }
    }
  }

  float linv[4];
#pragma unroll
  for (int r = 0; r < 4; ++r) linv[r] = 1.0f / l_run[r];
#pragma unroll
  for (int t = 0; t < 4; ++t)
#pragma unroll
    for (int r = 0; r < 4; ++r) {
      float val = Os[t][r] * linv[r] + Op[t][r];
      Xh[(size_t)(b * N_ + q0 + 16 * w + quad * 4 + r) * D_ + h * C_ + 16 * t + l15] =
          (_Float16)val;
    }
}

// ---------------------------------------------------------------------------
// mlp: Y = act(X @ W + bias). X f16 [4096][1024], Wt f16 [out][in] (transposed).
// 128x128 tile, BK=64, register-double-buffered staging (1 block/CU grid).
// ---------------------------------------------------------------------------
template <bool SILU, typename OT>
__global__ __launch_bounds__(256) void mlp_kernel(
    const _Float16* __restrict__ X, const _Float16* __restrict__ Wt,
    const float* __restrict__ bias, OT* __restrict__ Y)
{
  __shared__ __align__(16) _Float16 a_lds[128][72];  // [m][k]
  __shared__ __align__(16) _Float16 b_lds[128][72];  // [n][k]
  const int tid = threadIdx.x;
  const int n0 = blockIdx.x * 128, m0 = blockIdx.y * 128;
  const int lane = tid & 63, w = tid >> 6;
  const int wr = (w >> 1) * 64, wc = (w & 1) * 64;
  const int l15 = lane & 15, quad = lane >> 4;

  f32x4 acc[4][4];
#pragma unroll
  for (int rt = 0; rt < 4; ++rt)
#pragma unroll
    for (int ct = 0; ct < 4; ++ct) acc[rt][ct] = (f32x4){0.f, 0.f, 0.f, 0.f};

  uint4 ra[4], rb[4];
  // prologue: tile 0 -> regs -> LDS
#pragma unroll
  for (int i = 0; i < 4; ++i) {
    int idx = i * 256 + tid;
    int r = idx >> 3, c8 = (idx & 7) << 3;
    ra[i] = *(const uint4*)(X + (size_t)(m0 + r) * D_ + c8);
    rb[i] = *(const uint4*)(Wt + (size_t)(n0 + r) * D_ + c8);
  }
#pragma unroll
  for (int i = 0; i < 4; ++i) {
    int idx = i * 256 + tid;
    int r = idx >> 3, c8 = (idx & 7) << 3;
    *(uint4*)&a_lds[r][c8] = ra[i];
    *(uint4*)&b_lds[r][c8] = rb[i];
  }

  for (int kt = 0; kt < 16; ++kt) {
    __syncthreads();   // LDS tile kt ready
    if (kt < 15) {     // prefetch tile kt+1 global -> regs (latency hidden)
      int k0 = (kt + 1) * 64;
#pragma unroll
      for (int i = 0; i < 4; ++i) {
        int idx = i * 256 + tid;
        int r = idx >> 3, c8 = (idx & 7) << 3;
        ra[i] = *(const uint4*)(X + (size_t)(m0 + r) * D_ + k0 + c8);
        rb[i] = *(const uint4*)(Wt + (size_t)(n0 + r) * D_ + k0 + c8);
      }
    }
#pragma unroll
    for (int s = 0; s < 2; ++s) {
      half8 af[4], bf[4];
#pragma unroll
      for (int rt = 0; rt < 4; ++rt)
        af[rt] = *(const half8*)&a_lds[wr + rt * 16 + l15][s * 32 + quad * 8];
#pragma unroll
      for (int ct = 0; ct < 4; ++ct)
        bf[ct] = *(const half8*)&b_lds[wc + ct * 16 + l15][s * 32 + quad * 8];
#pragma unroll
      for (int rt = 0; rt < 4; ++rt)
#pragma unroll
        for (int ct = 0; ct < 4; ++ct)
          acc[rt][ct] = MFMA16(af[rt], bf[ct], acc[rt][ct]);
    }
    __syncthreads();   // all reads of tile kt done
    if (kt < 15) {
#pragma unroll
      for (int i = 0; i < 4; ++i) {
        int idx = i * 256 + tid;
        int r = idx >> 3, c8 = (idx & 7) << 3;
        *(uint4*)&a_lds[r][c8] = ra[i];
        *(uint4*)&b_lds[r][c8] = rb[i];
      }
    }
  }

  float bv[4];
#pragma unroll
  for (int ct = 0; ct < 4; ++ct) bv[ct] = bias[n0 + wc + ct * 16 + l15];
#pragma unroll
  for (int rt = 0; rt < 4; ++rt)
#pragma unroll
    for (int ct = 0; ct < 4; ++ct)
#pragma unroll
      for (int r = 0; r < 4; ++r) {
        float val = acc[rt][ct][r] + bv[ct];
        if (SILU) val = val / (1.f + __expf(-val));
        int row = m0 + wr + rt * 16 + quad * 4 + r;
        int col = n0 + wc + ct * 16 + l15;
        Y[(size_t)row * D_ + col] = (OT)val;
      }
}

// ---------------------------------------------------------------------------
extern "C" void kernel_launch(void* const* d_in, const int* in_sizes, int n_in,
                              void* d_out, int out_size, void* d_ws, size_t ws_size,
                              hipStream_t stream) {
  const float* q  = (const float*)d_in[0];
  const float* k  = (const float*)d_in[1];
  const float* v  = (const float*)d_in[2];
  const float* pe = (const float*)d_in[3];
  const float* w1 = (const float*)d_in[4];
  const float* b1 = (const float*)d_in[5];
  const float* w2 = (const float*)d_in[6];
  const float* b2 = (const float*)d_in[7];
  float* out = (float*)d_out;

  // d_out (16 MB) doubles as scratch: [0,8MB) X_f16, [8,16MB) V^T f16.
  // Both dead before mlp2 rewrites d_out with the final fp32 result.
  _Float16* Xh  = (_Float16*)d_out;
  _Float16* vth = (_Float16*)((char*)d_out + (size_t)8 * 1024 * 1024);
  // ws: [0,8MB) H1 f16, [8,10MB) W1^T f16, [10,12MB) W2^T f16
  _Float16* H1h = (_Float16*)d_ws;
  _Float16* w1t = (_Float16*)((char*)d_ws + (size_t)8 * 1024 * 1024);
  _Float16* w2t = (_Float16*)((char*)d_ws + (size_t)10 * 1024 * 1024);

  // weights: W [in][out] fp32 -> W^T [out][in] f16
  transpose_cvt<<<dim3(16, 16, 1), 256, 0, stream>>>(w1, w1t, D_, D_, 0, 0);
  transpose_cvt<<<dim3(16, 16, 1), 256, 0, stream>>>(w2, w2t, D_, D_, 0, 0);
  // v [bh][key][c] fp32 -> v^T [bh][c][key] f16
  transpose_cvt<<<dim3(16, 1, B_ * H_), 256, 0, stream>>>(
      v, vth, C_, N_, (long)N_ * C_, (long)N_ * C_);
  // attention (+ fused pe@v) -> X f16
  attn_kernel<<<dim3(B_ * H_ * (N_ / 64)), 256, 0, stream>>>(q, k, pe, vth, Xh);
  // MLP
  mlp_kernel<true, _Float16><<<dim3(D_ / 128, (B_ * N_) / 128), 256, 0, stream>>>(
      Xh, w1t, b1, H1h);
  mlp_kernel<false, float><<<dim3(D_ / 128, (B_ * N_) / 128), 256, 0, stream>>>(
      H1h, w2t, b2, out);
}

// Round 4
// 379.536 us; speedup vs baseline: 2.2147x; 1.1265x over previous
//
#include <hip/hip_runtime.h>

#define B_ 4
#define H_ 16
#define N_ 1024
#define C_ 64
#define D_ 1024

typedef _Float16 half8 __attribute__((ext_vector_type(8)));
typedef _Float16 half4v __attribute__((ext_vector_type(4)));
typedef float f32x4 __attribute__((ext_vector_type(4)));

#define MFMA16(a, b, c) __builtin_amdgcn_mfma_f32_16x16x32_f16(a, b, c, 0, 0, 0)

// ---------------------------------------------------------------------------
// transpose_cvt: out_f16[c][r] = (f16) in_f32[r][c], 64x64 tiles, batched (z)
// ---------------------------------------------------------------------------
__global__ __launch_bounds__(256) void transpose_cvt(
    const float* __restrict__ in, _Float16* __restrict__ outp,
    int in_stride, int out_stride, long in_bstride, long out_bstride)
{
  __shared__ float t[64][65];
  const int tid = threadIdx.x;
  const int r0 = blockIdx.x * 64, c0 = blockIdx.y * 64;
  const float* inb = in + (size_t)blockIdx.z * in_bstride;
  _Float16* outb = outp + (size_t)blockIdx.z * out_bstride;
#pragma unroll
  for (int i = 0; i < 4; ++i) {
    int idx = i * 256 + tid;
    int r = idx >> 4, c4 = (idx & 15) << 2;
    float4 a = *(const float4*)(inb + (size_t)(r0 + r) * in_stride + c0 + c4);
    t[r][c4] = a.x; t[r][c4 + 1] = a.y; t[r][c4 + 2] = a.z; t[r][c4 + 3] = a.w;
  }
  __syncthreads();
#pragma unroll
  for (int i = 0; i < 2; ++i) {
    int idx = i * 256 + tid;
    int rr = idx >> 3, c8 = (idx & 7) << 3;
    half8 hv;
#pragma unroll
    for (int j = 0; j < 8; ++j) hv[j] = (_Float16)t[c8 + j][rr];
    *(half8*)(outb + (size_t)(c0 + rr) * out_stride + r0 + c8) = hv;
  }
}

// ---------------------------------------------------------------------------
// pev: xpe[b*N+n][h*64+c] = sum_m pe[h][n][m] * v[b][h][m][c]
// One block per (n-tile 64, h). Cols = 256 = (b,c). Reads pe exactly once.
// Reg-prefetch double-buffered staging; wave tile 32x128 (acc 2x8).
// ---------------------------------------------------------------------------
__global__ __launch_bounds__(256, 2) void pev_kernel(
    const float* __restrict__ pe, const _Float16* __restrict__ vth,
    _Float16* __restrict__ xpe)
{
  __shared__ __align__(16) _Float16 a_lds[64][72];    // [n-row][k=m]
  __shared__ __align__(16) _Float16 b_lds[256][72];   // [col=(b*64+c)][k=m]
  const int tid = threadIdx.x;
  const int n0 = blockIdx.x * 64;
  const int h = blockIdx.y;
  const float* peb = pe + (size_t)h * N_ * N_ + (size_t)n0 * N_;

  const int lane = tid & 63, w = tid >> 6;
  const int l15 = lane & 15, quad = lane >> 4;
  const int wrow = (w >> 1) * 32, wcol = (w & 1) * 128;

  // per-thread staging coords
  const int ar[4] = { tid >> 4, (256 + tid) >> 4, (512 + tid) >> 4, (768 + tid) >> 4 };
  const int ac4 = (tid & 15) << 2;
  const _Float16* bsrc[8];
  int brow[8], bk8[8];
#pragma unroll
  for (int i = 0; i < 8; ++i) {
    int idx = i * 256 + tid;
    int col = idx >> 3, k8 = (idx & 7) << 3;
    int b = col >> 6, c = col & 63;
    bsrc[i] = vth + ((size_t)(b * H_ + h) * C_ + c) * N_ + k8;
    brow[i] = col;
    bk8[i] = k8;
  }

  f32x4 acc[2][8];
#pragma unroll
  for (int rt = 0; rt < 2; ++rt)
#pragma unroll
    for (int ct = 0; ct < 8; ++ct) acc[rt][ct] = (f32x4){0.f, 0.f, 0.f, 0.f};

  float4 areg[4];
  half8 breg[8];
  // prologue: tile 0
#pragma unroll
  for (int i = 0; i < 4; ++i) areg[i] = *(const float4*)(peb + (size_t)ar[i] * N_ + ac4);
#pragma unroll
  for (int i = 0; i < 8; ++i) breg[i] = *(const half8*)(bsrc[i]);
#pragma unroll
  for (int i = 0; i < 4; ++i) {
    half4v hv = {(_Float16)areg[i].x, (_Float16)areg[i].y,
                 (_Float16)areg[i].z, (_Float16)areg[i].w};
    *(half4v*)&a_lds[ar[i]][ac4] = hv;
  }
#pragma unroll
  for (int i = 0; i < 8; ++i) *(half8*)&b_lds[brow[i]][bk8[i]] = breg[i];

  for (int kt = 0; kt < 16; ++kt) {
    __syncthreads();
    if (kt < 15) {
      int m0 = (kt + 1) * 64;
#pragma unroll
      for (int i = 0; i < 4; ++i)
        areg[i] = *(const float4*)(peb + (size_t)ar[i] * N_ + m0 + ac4);
#pragma unroll
      for (int i = 0; i < 8; ++i) breg[i] = *(const half8*)(bsrc[i] + m0);
    }
#pragma unroll
    for (int s = 0; s < 2; ++s) {
      half8 af[2], bf[8];
#pragma unroll
      for (int rt = 0; rt < 2; ++rt)
        af[rt] = *(const half8*)&a_lds[wrow + rt * 16 + l15][s * 32 + quad * 8];
#pragma unroll
      for (int ct = 0; ct < 8; ++ct)
        bf[ct] = *(const half8*)&b_lds[wcol + ct * 16 + l15][s * 32 + quad * 8];
#pragma unroll
      for (int rt = 0; rt < 2; ++rt)
#pragma unroll
        for (int ct = 0; ct < 8; ++ct)
          acc[rt][ct] = MFMA16(af[rt], bf[ct], acc[rt][ct]);
    }
    __syncthreads();
    if (kt < 15) {
#pragma unroll
      for (int i = 0; i < 4; ++i) {
        half4v hv = {(_Float16)areg[i].x, (_Float16)areg[i].y,
                     (_Float16)areg[i].z, (_Float16)areg[i].w};
        *(half4v*)&a_lds[ar[i]][ac4] = hv;
      }
#pragma unroll
      for (int i = 0; i < 8; ++i) *(half8*)&b_lds[brow[i]][bk8[i]] = breg[i];
    }
  }

#pragma unroll
  for (int rt = 0; rt < 2; ++rt)
#pragma unroll
    for (int ct = 0; ct < 8; ++ct) {
      int col = wcol + ct * 16 + l15;
      int b = col >> 6, c = col & 63;
#pragma unroll
      for (int r = 0; r < 4; ++r) {
        int nrow = n0 + wrow + rt * 16 + quad * 4 + r;
        xpe[(size_t)(b * N_ + nrow) * D_ + h * C_ + c] = (_Float16)acc[rt][ct][r];
      }
    }
}

// ---------------------------------------------------------------------------
// attn: flash attention; pe handled by pev. Reg-prefetched K/V staging.
// out_f16[b,n,h*64+c] = softmax(q k^T/8) @ v + xpe
// ---------------------------------------------------------------------------
__global__ __launch_bounds__(256, 4) void attn_kernel(
    const float* __restrict__ q, const float* __restrict__ k,
    const _Float16* __restrict__ vth, const _Float16* __restrict__ xpe,
    _Float16* __restrict__ Xh)
{
  __shared__ __align__(16) _Float16 qs[64][72];   // [query][c]
  __shared__ __align__(16) _Float16 ks[64][72];   // [key][c]
  __shared__ __align__(16) _Float16 vst[64][72];  // [c][key]
  __shared__ __align__(16) _Float16 ps[64][72];   // [query][key] exp(S-m)

  const int tid = threadIdx.x;
  const int qt = blockIdx.x & 15;
  const int bh = blockIdx.x >> 4;
  const int h = bh & (H_ - 1);
  const int b = bh >> 4;
  const int q0 = qt * 64;

  const float* qb = q + ((size_t)bh * N_ + q0) * C_;
  const float* kb = k + (size_t)bh * N_ * C_;
  const _Float16* vb = vth + (size_t)bh * C_ * N_;

  const int lane = tid & 63;
  const int w = tid >> 6;
  const int l15 = lane & 15;
  const int quad = lane >> 4;
  const int arow = 16 * w + l15;

  // staging coords
  const int sr = tid >> 4, sc4 = (tid & 15) << 2;          // K: rows sr, sr+16, ...
  const int vr = tid >> 3, vc8 = (tid & 7) << 3;           // V: rows vr, vr+32

  // stage q tile once (pre-scaled by 0.125)
#pragma unroll
  for (int i = 0; i < 4; ++i) {
    int r = sr + i * 16;
    float4 t = *(const float4*)(qb + (size_t)r * C_ + sc4);
    half4v hv = { (_Float16)(t.x * 0.125f), (_Float16)(t.y * 0.125f),
                  (_Float16)(t.z * 0.125f), (_Float16)(t.w * 0.125f) };
    *(half4v*)&qs[r][sc4] = hv;
  }

  f32x4 Os[4];
  float m_run[4], l_run[4];
#pragma unroll
  for (int t = 0; t < 4; ++t) Os[t] = (f32x4){0.f, 0.f, 0.f, 0.f};
#pragma unroll
  for (int r = 0; r < 4; ++r) { m_run[r] = -3.0e38f; l_run[r] = 0.f; }

  float4 kreg[4];
  uint4 vreg[2];
  // prologue: tile 0 -> regs -> LDS
#pragma unroll
  for (int i = 0; i < 4; ++i)
    kreg[i] = *(const float4*)(kb + (size_t)(sr + i * 16) * C_ + sc4);
#pragma unroll
  for (int i = 0; i < 2; ++i)
    vreg[i] = *(const uint4*)(vb + (size_t)(vr + i * 32) * N_ + vc8);
#pragma unroll
  for (int i = 0; i < 4; ++i) {
    half4v hk = {(_Float16)kreg[i].x, (_Float16)kreg[i].y,
                 (_Float16)kreg[i].z, (_Float16)kreg[i].w};
    *(half4v*)&ks[sr + i * 16][sc4] = hk;
  }
#pragma unroll
  for (int i = 0; i < 2; ++i) *(uint4*)&vst[vr + i * 32][vc8] = vreg[i];

  for (int kt = 0; kt < 16; ++kt) {
    __syncthreads();   // LDS tile kt ready
    if (kt < 15) {     // prefetch tile kt+1
      int m0 = (kt + 1) * 64;
#pragma unroll
      for (int i = 0; i < 4; ++i)
        kreg[i] = *(const float4*)(kb + (size_t)(m0 + sr + i * 16) * C_ + sc4);
#pragma unroll
      for (int i = 0; i < 2; ++i)
        vreg[i] = *(const uint4*)(vb + (size_t)(vr + i * 32) * N_ + m0 + vc8);
    }

    // ---- S = Q K^T ----
    f32x4 sacc[4];
#pragma unroll
    for (int t = 0; t < 4; ++t) sacc[t] = (f32x4){0.f, 0.f, 0.f, 0.f};
#pragma unroll
    for (int s = 0; s < 2; ++s) {
      half8 aq = *(const half8*)&qs[arow][s * 32 + quad * 8];
#pragma unroll
      for (int t = 0; t < 4; ++t) {
        half8 bk = *(const half8*)&ks[16 * t + l15][s * 32 + quad * 8];
        sacc[t] = MFMA16(aq, bk, sacc[t]);
      }
    }

    // ---- online softmax ----
    float alpha[4];
#pragma unroll
    for (int r = 0; r < 4; ++r) {
      float mx = fmaxf(fmaxf(sacc[0][r], sacc[1][r]), fmaxf(sacc[2][r], sacc[3][r]));
      mx = fmaxf(mx, __shfl_xor(mx, 1));
      mx = fmaxf(mx, __shfl_xor(mx, 2));
      mx = fmaxf(mx, __shfl_xor(mx, 4));
      mx = fmaxf(mx, __shfl_xor(mx, 8));
      float nm = fmaxf(m_run[r], mx);
      alpha[r] = __expf(m_run[r] - nm);
      m_run[r] = nm;
      float rs = 0.f;
#pragma unroll
      for (int t = 0; t < 4; ++t) {
        float p = __expf(sacc[t][r] - nm);
        sacc[t][r] = p;
        rs += p;
      }
      rs += __shfl_xor(rs, 1);
      rs += __shfl_xor(rs, 2);
      rs += __shfl_xor(rs, 4);
      rs += __shfl_xor(rs, 8);
      l_run[r] = l_run[r] * alpha[r] + rs;
    }

    // write P (wave-private rows), rescale O
#pragma unroll
    for (int t = 0; t < 4; ++t)
#pragma unroll
      for (int r = 0; r < 4; ++r)
        ps[16 * w + quad * 4 + r][16 * t + l15] = (_Float16)sacc[t][r];
#pragma unroll
    for (int t = 0; t < 4; ++t)
#pragma unroll
      for (int r = 0; r < 4; ++r)
        Os[t][r] *= alpha[r];

    // ---- O += P V ----
#pragma unroll
    for (int s = 0; s < 2; ++s) {
      half8 ap = *(const half8*)&ps[arow][s * 32 + quad * 8];
#pragma unroll
      for (int t = 0; t < 4; ++t) {
        half8 bv = *(const half8*)&vst[16 * t + l15][s * 32 + quad * 8];
        Os[t] = MFMA16(ap, bv, Os[t]);
      }
    }

    __syncthreads();   // reads of tile kt done
    if (kt < 15) {
#pragma unroll
      for (int i = 0; i < 4; ++i) {
        half4v hk = {(_Float16)kreg[i].x, (_Float16)kreg[i].y,
                     (_Float16)kreg[i].z, (_Float16)kreg[i].w};
        *(half4v*)&ks[sr + i * 16][sc4] = hk;
      }
#pragma unroll
      for (int i = 0; i < 2; ++i) *(uint4*)&vst[vr + i * 32][vc8] = vreg[i];
    }
  }

  float linv[4];
#pragma unroll
  for (int r = 0; r < 4; ++r) linv[r] = 1.0f / l_run[r];
#pragma unroll
  for (int t = 0; t < 4; ++t)
#pragma unroll
    for (int r = 0; r < 4; ++r) {
      size_t o = (size_t)(b * N_ + q0 + 16 * w + quad * 4 + r) * D_ + h * C_ + 16 * t + l15;
      Xh[o] = (_Float16)(Os[t][r] * linv[r] + (float)xpe[o]);
    }
}

// ---------------------------------------------------------------------------
// mlp: Y = act(X @ W + bias). 64x128 tile (grid 512 = 2 blocks/CU), BK=64,
// register-double-buffered staging. Wave tile 32x64 (acc 2x4).
// ---------------------------------------------------------------------------
template <bool SILU, typename OT>
__global__ __launch_bounds__(256, 4) void mlp_kernel(
    const _Float16* __restrict__ X, const _Float16* __restrict__ Wt,
    const float* __restrict__ bias, OT* __restrict__ Y)
{
  __shared__ __align__(16) _Float16 a_lds[64][72];   // [m][k]
  __shared__ __align__(16) _Float16 b_lds[128][72];  // [n][k]
  const int tid = threadIdx.x;
  const int n0 = blockIdx.x * 128, m0 = blockIdx.y * 64;
  const int lane = tid & 63, w = tid >> 6;
  const int wr = (w >> 1) * 32, wc = (w & 1) * 64;
  const int l15 = lane & 15, quad = lane >> 4;
  const int arr = tid >> 3, ac8 = (tid & 7) << 3;   // A rows: arr, arr+32

  f32x4 acc[2][4];
#pragma unroll
  for (int rt = 0; rt < 2; ++rt)
#pragma unroll
    for (int ct = 0; ct < 4; ++ct) acc[rt][ct] = (f32x4){0.f, 0.f, 0.f, 0.f};

  uint4 ra[2], rb[4];
#pragma unroll
  for (int i = 0; i < 2; ++i)
    ra[i] = *(const uint4*)(X + (size_t)(m0 + arr + i * 32) * D_ + ac8);
#pragma unroll
  for (int i = 0; i < 4; ++i)
    rb[i] = *(const uint4*)(Wt + (size_t)(n0 + arr + i * 32) * D_ + ac8);
#pragma unroll
  for (int i = 0; i < 2; ++i) *(uint4*)&a_lds[arr + i * 32][ac8] = ra[i];
#pragma unroll
  for (int i = 0; i < 4; ++i) *(uint4*)&b_lds[arr + i * 32][ac8] = rb[i];

  for (int kt = 0; kt < 16; ++kt) {
    __syncthreads();
    if (kt < 15) {
      int k0 = (kt + 1) * 64;
#pragma unroll
      for (int i = 0; i < 2; ++i)
        ra[i] = *(const uint4*)(X + (size_t)(m0 + arr + i * 32) * D_ + k0 + ac8);
#pragma unroll
      for (int i = 0; i < 4; ++i)
        rb[i] = *(const uint4*)(Wt + (size_t)(n0 + arr + i * 32) * D_ + k0 + ac8);
    }
#pragma unroll
    for (int s = 0; s < 2; ++s) {
      half8 af[2], bf[4];
#pragma unroll
      for (int rt = 0; rt < 2; ++rt)
        af[rt] = *(const half8*)&a_lds[wr + rt * 16 + l15][s * 32 + quad * 8];
#pragma unroll
      for (int ct = 0; ct < 4; ++ct)
        bf[ct] = *(const half8*)&b_lds[wc + ct * 16 + l15][s * 32 + quad * 8];
#pragma unroll
      for (int rt = 0; rt < 2; ++rt)
#pragma unroll
        for (int ct = 0; ct < 4; ++ct)
          acc[rt][ct] = MFMA16(af[rt], bf[ct], acc[rt][ct]);
    }
    __syncthreads();
    if (kt < 15) {
#pragma unroll
      for (int i = 0; i < 2; ++i) *(uint4*)&a_lds[arr + i * 32][ac8] = ra[i];
#pragma unroll
      for (int i = 0; i < 4; ++i) *(uint4*)&b_lds[arr + i * 32][ac8] = rb[i];
    }
  }

  float bv[4];
#pragma unroll
  for (int ct = 0; ct < 4; ++ct) bv[ct] = bias[n0 + wc + ct * 16 + l15];
#pragma unroll
  for (int rt = 0; rt < 2; ++rt)
#pragma unroll
    for (int ct = 0; ct < 4; ++ct)
#pragma unroll
      for (int r = 0; r < 4; ++r) {
        float val = acc[rt][ct][r] + bv[ct];
        if (SILU) val = val / (1.f + __expf(-val));
        int row = m0 + wr + rt * 16 + quad * 4 + r;
        int col = n0 + wc + ct * 16 + l15;
        Y[(size_t)row * D_ + col] = (OT)val;
      }
}

// ---------------------------------------------------------------------------
extern "C" void kernel_launch(void* const* d_in, const int* in_sizes, int n_in,
                              void* d_out, int out_size, void* d_ws, size_t ws_size,
                              hipStream_t stream) {
  const float* q  = (const float*)d_in[0];
  const float* k  = (const float*)d_in[1];
  const float* v  = (const float*)d_in[2];
  const float* pe = (const float*)d_in[3];
  const float* w1 = (const float*)d_in[4];
  const float* b1 = (const float*)d_in[5];
  const float* w2 = (const float*)d_in[6];
  const float* b2 = (const float*)d_in[7];
  float* out = (float*)d_out;

  // d_out (16 MB): [0,8MB) X_f16 (attn out, dead after mlp1), [8,16MB) V^T f16
  // (dead after attn). ws: [0,8) xpe f16 -> reused as H1 after attn consumes
  // it; [8,10) W1^T f16; [10,12) W2^T f16.
  _Float16* Xh  = (_Float16*)d_out;
  _Float16* vth = (_Float16*)((char*)d_out + (size_t)8 * 1024 * 1024);
  _Float16* xpeH1 = (_Float16*)d_ws;
  _Float16* w1t = (_Float16*)((char*)d_ws + (size_t)8 * 1024 * 1024);
  _Float16* w2t = (_Float16*)((char*)d_ws + (size_t)10 * 1024 * 1024);

  transpose_cvt<<<dim3(16, 16, 1), 256, 0, stream>>>(w1, w1t, D_, D_, 0, 0);
  transpose_cvt<<<dim3(16, 16, 1), 256, 0, stream>>>(w2, w2t, D_, D_, 0, 0);
  transpose_cvt<<<dim3(16, 1, B_ * H_), 256, 0, stream>>>(
      v, vth, C_, N_, (long)N_ * C_, (long)N_ * C_);
  // xpe = pe @ v (pe read exactly once)
  pev_kernel<<<dim3(N_ / 64, H_), 256, 0, stream>>>(pe, vth, xpeH1);
  // flash attention + xpe -> X f16
  attn_kernel<<<dim3(B_ * H_ * (N_ / 64)), 256, 0, stream>>>(q, k, vth, xpeH1, Xh);
  // MLP
  mlp_kernel<true, _Float16><<<dim3(D_ / 128, (B_ * N_) / 64), 256, 0, stream>>>(
      Xh, w1t, b1, xpeH1);
  mlp_kernel<false, float><<<dim3(D_ / 128, (B_ * N_) / 64), 256, 0, stream>>>(
      xpeH1, w2t, b2, out);
}

// Round 5
// 340.343 us; speedup vs baseline: 2.4698x; 1.1152x over previous
//
#include <hip/hip_runtime.h>

#define B_ 4
#define H_ 16
#define N_ 1024
#define C_ 64
#define D_ 1024

typedef _Float16 half8 __attribute__((ext_vector_type(8)));
typedef _Float16 half4v __attribute__((ext_vector_type(4)));
typedef float f32x4 __attribute__((ext_vector_type(4)));

#define MFMA16(a, b, c) __builtin_amdgcn_mfma_f32_16x16x32_f16(a, b, c, 0, 0, 0)

// ---------------------------------------------------------------------------
// transpose_cvt: out_f16[c][r] = (f16) in_f32[r][c], 64x64 tiles, batched (z)
// ---------------------------------------------------------------------------
__global__ __launch_bounds__(256) void transpose_cvt(
    const float* __restrict__ in, _Float16* __restrict__ outp,
    int in_stride, int out_stride, long in_bstride, long out_bstride)
{
  __shared__ float t[64][65];
  const int tid = threadIdx.x;
  const int r0 = blockIdx.x * 64, c0 = blockIdx.y * 64;
  const float* inb = in + (size_t)blockIdx.z * in_bstride;
  _Float16* outb = outp + (size_t)blockIdx.z * out_bstride;
#pragma unroll
  for (int i = 0; i < 4; ++i) {
    int idx = i * 256 + tid;
    int r = idx >> 4, c4 = (idx & 15) << 2;
    float4 a = *(const float4*)(inb + (size_t)(r0 + r) * in_stride + c0 + c4);
    t[r][c4] = a.x; t[r][c4 + 1] = a.y; t[r][c4 + 2] = a.z; t[r][c4 + 3] = a.w;
  }
  __syncthreads();
#pragma unroll
  for (int i = 0; i < 2; ++i) {
    int idx = i * 256 + tid;
    int rr = idx >> 3, c8 = (idx & 7) << 3;
    half8 hv;
#pragma unroll
    for (int j = 0; j < 8; ++j) hv[j] = (_Float16)t[c8 + j][rr];
    *(half8*)(outb + (size_t)(c0 + rr) * out_stride + r0 + c8) = hv;
  }
}

// ---------------------------------------------------------------------------
// pev: xpe[b*N+n][h*64+c] = sum_m pe[h][n][m] * v[b][h][m][c]
// One block per (n-tile 64, h). Cols = 256 = (b,c). Reads pe exactly once.
// ---------------------------------------------------------------------------
__global__ __launch_bounds__(256, 2) void pev_kernel(
    const float* __restrict__ pe, const _Float16* __restrict__ vth,
    _Float16* __restrict__ xpe)
{
  __shared__ __align__(16) _Float16 a_lds[64][72];    // [n-row][k=m]
  __shared__ __align__(16) _Float16 b_lds[256][72];   // [col=(b*64+c)][k=m]
  const int tid = threadIdx.x;
  const int n0 = blockIdx.x * 64;
  const int h = blockIdx.y;
  const float* peb = pe + (size_t)h * N_ * N_ + (size_t)n0 * N_;

  const int lane = tid & 63, w = tid >> 6;
  const int l15 = lane & 15, quad = lane >> 4;
  const int wrow = (w >> 1) * 32, wcol = (w & 1) * 128;

  const int ar[4] = { tid >> 4, (256 + tid) >> 4, (512 + tid) >> 4, (768 + tid) >> 4 };
  const int ac4 = (tid & 15) << 2;
  const _Float16* bsrc[8];
  int brow[8], bk8[8];
#pragma unroll
  for (int i = 0; i < 8; ++i) {
    int idx = i * 256 + tid;
    int col = idx >> 3, k8 = (idx & 7) << 3;
    int b = col >> 6, c = col & 63;
    bsrc[i] = vth + ((size_t)(b * H_ + h) * C_ + c) * N_ + k8;
    brow[i] = col;
    bk8[i] = k8;
  }

  f32x4 acc[2][8];
#pragma unroll
  for (int rt = 0; rt < 2; ++rt)
#pragma unroll
    for (int ct = 0; ct < 8; ++ct) acc[rt][ct] = (f32x4){0.f, 0.f, 0.f, 0.f};

  float4 areg[4];
  half8 breg[8];
#pragma unroll
  for (int i = 0; i < 4; ++i) areg[i] = *(const float4*)(peb + (size_t)ar[i] * N_ + ac4);
#pragma unroll
  for (int i = 0; i < 8; ++i) breg[i] = *(const half8*)(bsrc[i]);
#pragma unroll
  for (int i = 0; i < 4; ++i) {
    half4v hv = {(_Float16)areg[i].x, (_Float16)areg[i].y,
                 (_Float16)areg[i].z, (_Float16)areg[i].w};
    *(half4v*)&a_lds[ar[i]][ac4] = hv;
  }
#pragma unroll
  for (int i = 0; i < 8; ++i) *(half8*)&b_lds[brow[i]][bk8[i]] = breg[i];

  for (int kt = 0; kt < 16; ++kt) {
    __syncthreads();
    if (kt < 15) {
      int m0 = (kt + 1) * 64;
#pragma unroll
      for (int i = 0; i < 4; ++i)
        areg[i] = *(const float4*)(peb + (size_t)ar[i] * N_ + m0 + ac4);
#pragma unroll
      for (int i = 0; i < 8; ++i) breg[i] = *(const half8*)(bsrc[i] + m0);
    }
#pragma unroll
    for (int s = 0; s < 2; ++s) {
      half8 af[2], bf[8];
#pragma unroll
      for (int rt = 0; rt < 2; ++rt)
        af[rt] = *(const half8*)&a_lds[wrow + rt * 16 + l15][s * 32 + quad * 8];
#pragma unroll
      for (int ct = 0; ct < 8; ++ct)
        bf[ct] = *(const half8*)&b_lds[wcol + ct * 16 + l15][s * 32 + quad * 8];
#pragma unroll
      for (int rt = 0; rt < 2; ++rt)
#pragma unroll
        for (int ct = 0; ct < 8; ++ct)
          acc[rt][ct] = MFMA16(af[rt], bf[ct], acc[rt][ct]);
    }
    __syncthreads();
    if (kt < 15) {
#pragma unroll
      for (int i = 0; i < 4; ++i) {
        half4v hv = {(_Float16)areg[i].x, (_Float16)areg[i].y,
                     (_Float16)areg[i].z, (_Float16)areg[i].w};
        *(half4v*)&a_lds[ar[i]][ac4] = hv;
      }
#pragma unroll
      for (int i = 0; i < 8; ++i) *(half8*)&b_lds[brow[i]][bk8[i]] = breg[i];
    }
  }

#pragma unroll
  for (int rt = 0; rt < 2; ++rt)
#pragma unroll
    for (int ct = 0; ct < 8; ++ct) {
      int col = wcol + ct * 16 + l15;
      int b = col >> 6, c = col & 63;
#pragma unroll
      for (int r = 0; r < 4; ++r) {
        int nrow = n0 + wrow + rt * 16 + quad * 4 + r;
        xpe[(size_t)(b * N_ + nrow) * D_ + h * C_ + c] = (_Float16)acc[rt][ct][r];
      }
    }
}

// ---------------------------------------------------------------------------
// attn: flash attention, 128-query tile. Grid 512, XCD-swizzled: idx = qt*64+bh
// so the 8 q-blocks of one (b,h) share an XCD's L2 for K/V.
// Wave w owns query rows 32w..32w+31 (2 A-fragment groups).
// ---------------------------------------------------------------------------
__global__ __launch_bounds__(256, 2) void attn_kernel(
    const float* __restrict__ q, const float* __restrict__ k,
    const _Float16* __restrict__ vth, const _Float16* __restrict__ xpe,
    _Float16* __restrict__ Xh)
{
  __shared__ __align__(16) _Float16 qs[128][72];  // [query][c]
  __shared__ __align__(16) _Float16 ks[64][72];   // [key][c]
  __shared__ __align__(16) _Float16 vst[64][72];  // [c][key]
  __shared__ __align__(16) _Float16 ps[128][72];  // [query][key] exp(S-m)

  const int tid = threadIdx.x;
  const int bh = blockIdx.x & 63;
  const int qt = blockIdx.x >> 6;
  const int h = bh & (H_ - 1);
  const int b = bh >> 4;
  const int q0 = qt * 128;

  const float* qb = q + ((size_t)bh * N_ + q0) * C_;
  const float* kb = k + (size_t)bh * N_ * C_;
  const _Float16* vb = vth + (size_t)bh * C_ * N_;

  const int lane = tid & 63;
  const int w = tid >> 6;
  const int l15 = lane & 15;
  const int quad = lane >> 4;

  // staging coords
  const int sr = tid >> 4, sc4 = (tid & 15) << 2;  // K: rows sr + 16i
  const int vr = tid >> 3, vc8 = (tid & 7) << 3;   // V: rows vr, vr+32

  // stage q tile once (128 rows, pre-scaled by 0.125)
#pragma unroll
  for (int i = 0; i < 8; ++i) {
    int idx = i * 256 + tid;
    int r = idx >> 4, c4 = (idx & 15) << 2;
    float4 t = *(const float4*)(qb + (size_t)r * C_ + c4);
    half4v hv = { (_Float16)(t.x * 0.125f), (_Float16)(t.y * 0.125f),
                  (_Float16)(t.z * 0.125f), (_Float16)(t.w * 0.125f) };
    *(half4v*)&qs[r][c4] = hv;
  }

  f32x4 Os[2][4];
  float m_run[2][4], l_run[2][4];
#pragma unroll
  for (int g = 0; g < 2; ++g)
#pragma unroll
    for (int t = 0; t < 4; ++t) Os[g][t] = (f32x4){0.f, 0.f, 0.f, 0.f};
#pragma unroll
  for (int g = 0; g < 2; ++g)
#pragma unroll
    for (int r = 0; r < 4; ++r) { m_run[g][r] = -3.0e38f; l_run[g][r] = 0.f; }

  float4 kreg[4];
  uint4 vreg[2];
#pragma unroll
  for (int i = 0; i < 4; ++i)
    kreg[i] = *(const float4*)(kb + (size_t)(sr + i * 16) * C_ + sc4);
#pragma unroll
  for (int i = 0; i < 2; ++i)
    vreg[i] = *(const uint4*)(vb + (size_t)(vr + i * 32) * N_ + vc8);
#pragma unroll
  for (int i = 0; i < 4; ++i) {
    half4v hk = {(_Float16)kreg[i].x, (_Float16)kreg[i].y,
                 (_Float16)kreg[i].z, (_Float16)kreg[i].w};
    *(half4v*)&ks[sr + i * 16][sc4] = hk;
  }
#pragma unroll
  for (int i = 0; i < 2; ++i) *(uint4*)&vst[vr + i * 32][vc8] = vreg[i];

  for (int kt = 0; kt < 16; ++kt) {
    __syncthreads();   // LDS tile kt ready
    if (kt < 15) {     // prefetch tile kt+1 into regs
      int m0 = (kt + 1) * 64;
#pragma unroll
      for (int i = 0; i < 4; ++i)
        kreg[i] = *(const float4*)(kb + (size_t)(m0 + sr + i * 16) * C_ + sc4);
#pragma unroll
      for (int i = 0; i < 2; ++i)
        vreg[i] = *(const uint4*)(vb + (size_t)(vr + i * 32) * N_ + m0 + vc8);
    }

    // ---- S = Q K^T : 2 row-groups x 4 key-tiles ----
    f32x4 sacc[2][4];
#pragma unroll
    for (int g = 0; g < 2; ++g)
#pragma unroll
      for (int t = 0; t < 4; ++t) sacc[g][t] = (f32x4){0.f, 0.f, 0.f, 0.f};
#pragma unroll
    for (int s = 0; s < 2; ++s) {
      half8 bk[4];
#pragma unroll
      for (int t = 0; t < 4; ++t)
        bk[t] = *(const half8*)&ks[16 * t + l15][s * 32 + quad * 8];
#pragma unroll
      for (int g = 0; g < 2; ++g) {
        half8 aq = *(const half8*)&qs[32 * w + 16 * g + l15][s * 32 + quad * 8];
#pragma unroll
        for (int t = 0; t < 4; ++t) sacc[g][t] = MFMA16(aq, bk[t], sacc[g][t]);
      }
    }

    // ---- online softmax per row-group ----
#pragma unroll
    for (int g = 0; g < 2; ++g) {
      float alpha[4];
#pragma unroll
      for (int r = 0; r < 4; ++r) {
        float mx = fmaxf(fmaxf(sacc[g][0][r], sacc[g][1][r]),
                         fmaxf(sacc[g][2][r], sacc[g][3][r]));
        mx = fmaxf(mx, __shfl_xor(mx, 1));
        mx = fmaxf(mx, __shfl_xor(mx, 2));
        mx = fmaxf(mx, __shfl_xor(mx, 4));
        mx = fmaxf(mx, __shfl_xor(mx, 8));
        float nm = fmaxf(m_run[g][r], mx);
        alpha[r] = __expf(m_run[g][r] - nm);
        m_run[g][r] = nm;
        float rs = 0.f;
#pragma unroll
        for (int t = 0; t < 4; ++t) {
          float p = __expf(sacc[g][t][r] - nm);
          sacc[g][t][r] = p;
          rs += p;
        }
        rs += __shfl_xor(rs, 1);
        rs += __shfl_xor(rs, 2);
        rs += __shfl_xor(rs, 4);
        rs += __shfl_xor(rs, 8);
        l_run[g][r] = l_run[g][r] * alpha[r] + rs;
      }
      // write P rows (wave-private), rescale O
#pragma unroll
      for (int t = 0; t < 4; ++t)
#pragma unroll
        for (int r = 0; r < 4; ++r)
          ps[32 * w + 16 * g + quad * 4 + r][16 * t + l15] = (_Float16)sacc[g][t][r];
#pragma unroll
      for (int t = 0; t < 4; ++t)
#pragma unroll
        for (int r = 0; r < 4; ++r)
          Os[g][t][r] *= alpha[r];
    }

    // ---- O += P V ----
#pragma unroll
    for (int s = 0; s < 2; ++s) {
      half8 bv[4];
#pragma unroll
      for (int t = 0; t < 4; ++t)
        bv[t] = *(const half8*)&vst[16 * t + l15][s * 32 + quad * 8];
#pragma unroll
      for (int g = 0; g < 2; ++g) {
        half8 ap = *(const half8*)&ps[32 * w + 16 * g + l15][s * 32 + quad * 8];
#pragma unroll
        for (int t = 0; t < 4; ++t) Os[g][t] = MFMA16(ap, bv[t], Os[g][t]);
      }
    }

    __syncthreads();   // reads of tile kt done
    if (kt < 15) {
#pragma unroll
      for (int i = 0; i < 4; ++i) {
        half4v hk = {(_Float16)kreg[i].x, (_Float16)kreg[i].y,
                     (_Float16)kreg[i].z, (_Float16)kreg[i].w};
        *(half4v*)&ks[sr + i * 16][sc4] = hk;
      }
#pragma unroll
      for (int i = 0; i < 2; ++i) *(uint4*)&vst[vr + i * 32][vc8] = vreg[i];
    }
  }

#pragma unroll
  for (int g = 0; g < 2; ++g) {
    float linv[4];
#pragma unroll
    for (int r = 0; r < 4; ++r) linv[r] = 1.0f / l_run[g][r];
#pragma unroll
    for (int t = 0; t < 4; ++t)
#pragma unroll
      for (int r = 0; r < 4; ++r) {
        size_t o = (size_t)(b * N_ + q0 + 32 * w + 16 * g + quad * 4 + r) * D_
                 + h * C_ + 16 * t + l15;
        Xh[o] = (_Float16)(Os[g][t][r] * linv[r] + (float)xpe[o]);
      }
  }
}

// ---------------------------------------------------------------------------
// mlp: Y = act(X @ W + bias). 128x128 tile, BK=64, ping-pong LDS (ONE barrier
// per K-tile). Grid 256 (8 x 32) = 1 block/CU. Wave tile 64x64 (4x4 acc).
// ---------------------------------------------------------------------------
template <bool SILU, typename OT>
__global__ __launch_bounds__(256) void mlp_kernel(
    const _Float16* __restrict__ X, const _Float16* __restrict__ Wt,
    const float* __restrict__ bias, OT* __restrict__ Y)
{
  __shared__ __align__(16) _Float16 a_lds[2][128][72];  // [buf][m][k]
  __shared__ __align__(16) _Float16 b_lds[2][128][72];  // [buf][n][k]
  const int tid = threadIdx.x;
  const int n0 = blockIdx.x * 128, m0 = blockIdx.y * 128;
  const int lane = tid & 63, w = tid >> 6;
  const int wr = (w >> 1) * 64, wc = (w & 1) * 64;
  const int l15 = lane & 15, quad = lane >> 4;
  const int sr = tid >> 3, sc8 = (tid & 7) << 3;  // staging rows sr + 32i

  f32x4 acc[4][4];
#pragma unroll
  for (int rt = 0; rt < 4; ++rt)
#pragma unroll
    for (int ct = 0; ct < 4; ++ct) acc[rt][ct] = (f32x4){0.f, 0.f, 0.f, 0.f};

  uint4 ra[4], rb[4];
  // tile 0 -> regs -> buf0 ; tile 1 -> regs
#pragma unroll
  for (int i = 0; i < 4; ++i) {
    ra[i] = *(const uint4*)(X + (size_t)(m0 + sr + i * 32) * D_ + sc8);
    rb[i] = *(const uint4*)(Wt + (size_t)(n0 + sr + i * 32) * D_ + sc8);
  }
#pragma unroll
  for (int i = 0; i < 4; ++i) {
    *(uint4*)&a_lds[0][sr + i * 32][sc8] = ra[i];
    *(uint4*)&b_lds[0][sr + i * 32][sc8] = rb[i];
  }
#pragma unroll
  for (int i = 0; i < 4; ++i) {
    ra[i] = *(const uint4*)(X + (size_t)(m0 + sr + i * 32) * D_ + 64 + sc8);
    rb[i] = *(const uint4*)(Wt + (size_t)(n0 + sr + i * 32) * D_ + 64 + sc8);
  }
  __syncthreads();

  for (int kt = 0; kt < 16; ++kt) {
    const int cur = kt & 1;
    if (kt < 15) {  // store tile kt+1 regs -> other buffer (free since kt-1)
#pragma unroll
      for (int i = 0; i < 4; ++i) {
        *(uint4*)&a_lds[cur ^ 1][sr + i * 32][sc8] = ra[i];
        *(uint4*)&b_lds[cur ^ 1][sr + i * 32][sc8] = rb[i];
      }
    }
    if (kt < 14) {  // prefetch tile kt+2 -> regs
      int k0 = (kt + 2) * 64;
#pragma unroll
      for (int i = 0; i < 4; ++i) {
        ra[i] = *(const uint4*)(X + (size_t)(m0 + sr + i * 32) * D_ + k0 + sc8);
        rb[i] = *(const uint4*)(Wt + (size_t)(n0 + sr + i * 32) * D_ + k0 + sc8);
      }
    }
#pragma unroll
    for (int s = 0; s < 2; ++s) {
      half8 af[4], bf[4];
#pragma unroll
      for (int rt = 0; rt < 4; ++rt)
        af[rt] = *(const half8*)&a_lds[cur][wr + rt * 16 + l15][s * 32 + quad * 8];
#pragma unroll
      for (int ct = 0; ct < 4; ++ct)
        bf[ct] = *(const half8*)&b_lds[cur][wc + ct * 16 + l15][s * 32 + quad * 8];
#pragma unroll
      for (int rt = 0; rt < 4; ++rt)
#pragma unroll
        for (int ct = 0; ct < 4; ++ct)
          acc[rt][ct] = MFMA16(af[rt], bf[ct], acc[rt][ct]);
    }
    __syncthreads();  // tile kt reads done; buf cur^1 (tile kt+1) complete
  }

  float bv[4];
#pragma unroll
  for (int ct = 0; ct < 4; ++ct) bv[ct] = bias[n0 + wc + ct * 16 + l15];
#pragma unroll
  for (int rt = 0; rt < 4; ++rt)
#pragma unroll
    for (int ct = 0; ct < 4; ++ct)
#pragma unroll
      for (int r = 0; r < 4; ++r) {
        float val = acc[rt][ct][r] + bv[ct];
        if (SILU) val = val / (1.f + __expf(-val));
        int row = m0 + wr + rt * 16 + quad * 4 + r;
        int col = n0 + wc + ct * 16 + l15;
        Y[(size_t)row * D_ + col] = (OT)val;
      }
}

// ---------------------------------------------------------------------------
extern "C" void kernel_launch(void* const* d_in, const int* in_sizes, int n_in,
                              void* d_out, int out_size, void* d_ws, size_t ws_size,
                              hipStream_t stream) {
  const float* q  = (const float*)d_in[0];
  const float* k  = (const float*)d_in[1];
  const float* v  = (const float*)d_in[2];
  const float* pe = (const float*)d_in[3];
  const float* w1 = (const float*)d_in[4];
  const float* b1 = (const float*)d_in[5];
  const float* w2 = (const float*)d_in[6];
  const float* b2 = (const float*)d_in[7];
  float* out = (float*)d_out;

  // d_out (16 MB): [0,8) X_f16 (dead after mlp1), [8,16) V^T f16 (dead after
  // attn) — both dead before mlp2 overwrites d_out with the fp32 result.
  // ws: [0,8) xpe f16 -> reused as H1 after attn; [8,10) W1^T; [10,12) W2^T.
  _Float16* Xh  = (_Float16*)d_out;
  _Float16* vth = (_Float16*)((char*)d_out + (size_t)8 * 1024 * 1024);
  _Float16* xpeH1 = (_Float16*)d_ws;
  _Float16* w1t = (_Float16*)((char*)d_ws + (size_t)8 * 1024 * 1024);
  _Float16* w2t = (_Float16*)((char*)d_ws + (size_t)10 * 1024 * 1024);

  transpose_cvt<<<dim3(16, 16, 1), 256, 0, stream>>>(w1, w1t, D_, D_, 0, 0);
  transpose_cvt<<<dim3(16, 16, 1), 256, 0, stream>>>(w2, w2t, D_, D_, 0, 0);
  transpose_cvt<<<dim3(16, 1, B_ * H_), 256, 0, stream>>>(
      v, vth, C_, N_, (long)N_ * C_, (long)N_ * C_);
  // xpe = pe @ v (pe read exactly once)
  pev_kernel<<<dim3(N_ / 64, H_), 256, 0, stream>>>(pe, vth, xpeH1);
  // flash attention + xpe -> X f16 (XCD-swizzled 1D grid)
  attn_kernel<<<dim3(B_ * H_ * (N_ / 128)), 256, 0, stream>>>(q, k, vth, xpeH1, Xh);
  // MLP
  mlp_kernel<true, _Float16><<<dim3(D_ / 128, (B_ * N_) / 128), 256, 0, stream>>>(
      Xh, w1t, b1, xpeH1);
  mlp_kernel<false, float><<<dim3(D_ / 128, (B_ * N_) / 128), 256, 0, stream>>>(
      xpeH1, w2t, b2, out);
}